// Round 7
// baseline (166.564 us; speedup 1.0000x reference)
//
#include <hip/hip_runtime.h>

// SpectralConv2D: out[f,row,col,q] = relu( sum_{k=0..8} Lambda[phi] * Yflat[phi*128+q] )
// Two-pass: (1) compute the 8.13MB result plane -> out[filter 0];
// (2) fill-shaped broadcast: each block copies ONE contiguous 64KB chunk of
// plane 0 to ONE destination plane (register-staged, nontemporal stores).

#define L_TOT    15876            // 126*126
#define PLANE_F4 (L_TOT * 32)     // f4 per filter plane = 508,032
#define CHUNK_F4 4096             // f4 per pass-2 block (64KB), 16 per thread
#define CPP      125              // chunks per plane: 124 full + 1 partial (128 f4)

typedef float f4 __attribute__((ext_vector_type(4)));

__global__ __launch_bounds__(256) void spectral_compute(
    const float* __restrict__ x, const float* __restrict__ lam,
    float* __restrict__ out)
{
    const int t = threadIdx.x;
    const int l = blockIdx.x * 2 + (t >> 7);
    const int q = t & 127;
    const int row = l / 126;
    const int col = l - row * 126;

    float acc = 0.0f;
#pragma unroll
    for (int b3 = 0; b3 < 3; ++b3) {
#pragma unroll
        for (int j = 0; j < 3; ++j) {
            const unsigned phi = (unsigned)((3 * row + b3) * 378 + 3 * col + j);
            const unsigned n   = phi * 128u + (unsigned)q;  // fits u32
            const unsigned c   = n / 142884u;               // 378*378
            const unsigned rem = n - c * 142884u;
            const unsigned r   = rem / 378u;
            const unsigned ss  = rem - r * 378u;
            const unsigned src = c * 16384u + (r / 3u + r % 3u) * 128u + (ss / 3u + ss % 3u);
            acc = fmaf(x[src], lam[phi], acc);
        }
    }
    out[(size_t)l * 128 + q] = fmaxf(acc, 0.0f);  // filter-0 plane
}

__global__ __launch_bounds__(256) void spectral_bcast(float* __restrict__ out)
{
    const int t = threadIdx.x;
    const int b = blockIdx.x;
    const int f = b / CPP + 1;               // destination plane 1..63
    const int c = b - (f - 1) * CPP;         // chunk within plane
    const size_t cbase = (size_t)c * CHUNK_F4;

    const f4* p0 = (const f4*)out;           // plane 0 (source)
    f4* dst = (f4*)out + (size_t)f * PLANE_F4 + cbase;

    f4  v[16];
    bool ok[16];
#pragma unroll
    for (int k = 0; k < 16; ++k) {
        const int idx = t + k * 256;
        ok[k] = (cbase + (size_t)idx) < (size_t)PLANE_F4;
        v[k]  = ok[k] ? p0[cbase + idx] : (f4){0.f, 0.f, 0.f, 0.f};
    }
#pragma unroll
    for (int k = 0; k < 16; ++k) {
        if (ok[k]) __builtin_nontemporal_store(v[k], &dst[t + k * 256]);
    }
}

extern "C" void kernel_launch(void* const* d_in, const int* in_sizes, int n_in,
                              void* d_out, int out_size, void* d_ws, size_t ws_size,
                              hipStream_t stream) {
    const float* x   = (const float*)d_in[0];   // (1,128,128,128) f32
    const float* lam = (const float*)d_in[1];   // (1, 142884) f32
    float* out = (float*)d_out;                 // (64,126,126,128) f32

    spectral_compute<<<L_TOT / 2, 256, 0, stream>>>(x, lam, out);
    spectral_bcast<<<63 * CPP, 256, 0, stream>>>(out);
}

// Round 8
// 106.196 us; speedup vs baseline: 1.5685x; 1.5685x over previous
//
#include <hip/hip_runtime.h>

// SpectralConv2D: out[f,row,col,q] = relu( sum_{k=0..8} Lambda[phi] * Yflat[phi*128+q] )
// phi = (3*row+block)*378 + (3*col+j);  Yflat is flattened (C=128,R=378,S=378) with
// Y[c,r,s] = raw[c*16384 + (r/3+r%3)*128 + (s/3+s%3)];  broadcast over f=0..63.
// Fused single-pass (R4 structure), PLAIN cached stores (A/B vs nontemporal).

#define L_TOT 15876   // 126*126
#define L32   (L_TOT * 32)   // f4 per filter plane
#define LPB   4              // l-rows per block

typedef float f4 __attribute__((ext_vector_type(4)));

__global__ __launch_bounds__(256) void spectral_kernel(
    const float* __restrict__ x, const float* __restrict__ lam,
    float* __restrict__ out)
{
    __shared__ float s[LPB * 128];     // 4 rows of 128
    const int t  = threadIdx.x;        // 0..255
    const int l0 = blockIdx.x * LPB;
    const int q  = t & 127;

    // Each thread computes rows (t>>7) and (t>>7)+2.
#pragma unroll
    for (int li = (t >> 7); li < LPB; li += 2) {
        const int l = l0 + li;
        const int row = l / 126;
        const int col = l - row * 126;
        float acc = 0.0f;
#pragma unroll
        for (int b3 = 0; b3 < 3; ++b3) {
#pragma unroll
            for (int j = 0; j < 3; ++j) {
                const unsigned phi = (unsigned)((3 * row + b3) * 378 + 3 * col + j);
                const unsigned n   = phi * 128u + (unsigned)q;  // fits u32
                const unsigned c   = n / 142884u;               // 378*378
                const unsigned rem = n - c * 142884u;
                const unsigned r   = rem / 378u;
                const unsigned ss  = rem - r * 378u;
                const unsigned src = c * 16384u + (r / 3u + r % 3u) * 128u + (ss / 3u + ss % 3u);
                acc = fmaf(x[src], lam[phi], acc);
            }
        }
        s[li * 128 + q] = fmaxf(acc, 0.0f);
    }
    __syncthreads();

    // Broadcast to 64 filter planes. Iteration i writes filters 2i,2i+1 as two
    // full 2KB contiguous chunks (128 f4 each). Plain cached stores.
    const f4* s4 = (const f4*)s;       // 128 f4 covering the 4 rows
    f4* out4 = (f4*)out;
    const size_t lbase = (size_t)l0 * 32;
#pragma unroll
    for (int i = 0; i < 32; ++i) {
        const int idx = i * 256 + t;   // 0..8191
        const int f = idx >> 7;        // filter 0..63
        const int v = idx & 127;       // f4 index within 4-row chunk
        out4[(size_t)f * L32 + lbase + v] = s4[v];
    }
}

extern "C" void kernel_launch(void* const* d_in, const int* in_sizes, int n_in,
                              void* d_out, int out_size, void* d_ws, size_t ws_size,
                              hipStream_t stream) {
    const float* x   = (const float*)d_in[0];   // (1,128,128,128) f32
    const float* lam = (const float*)d_in[1];   // (1, 142884) f32
    float* out = (float*)d_out;                 // (64,126,126,128) f32

    spectral_kernel<<<L_TOT / LPB, 256, 0, stream>>>(x, lam, out);
}

// Round 9
// 106.053 us; speedup vs baseline: 1.5706x; 1.0014x over previous
//
#include <hip/hip_runtime.h>

// SpectralConv2D: out[f,row,col,q] = relu( sum_{k=0..8} Lambda[phi] * Yflat[phi*128+q] )
// phi = (3*row+block)*378 + (3*col+j);  Yflat is flattened (C=128,R=378,S=378) with
// Y[c,r,s] = raw[c*16384 + (r/3+r%3)*128 + (s/3+s%3)];  broadcast over f=0..63.
// R4 structure (fused, LPB=4, nontemporal stores) + bijective XCD-contiguity
// swizzle: each XCD owns a contiguous l-range so its 64 per-plane write fronts
// advance linearly (DRAM page locality on the L2 drain).

#define L_TOT 15876   // 126*126
#define L32   (L_TOT * 32)   // f4 per filter plane
#define LPB   4              // l-rows per block
#define NWG   (L_TOT / LPB)  // 3969 workgroups
#define NXCD  8

typedef float f4 __attribute__((ext_vector_type(4)));

__global__ __launch_bounds__(256) void spectral_kernel(
    const float* __restrict__ x, const float* __restrict__ lam,
    float* __restrict__ out)
{
    __shared__ float s[LPB * 128];     // 4 rows of 128
    const int t  = threadIdx.x;        // 0..255
    const int q  = t & 127;

    // Bijective XCD swizzle (m204): dispatch round-robins XCDs; remap so each
    // XCD gets a contiguous block range. nwg=3969: quo=496, rem=1.
    const int bid = blockIdx.x;
    const int quo = NWG / NXCD;        // 496
    const int rem = NWG % NXCD;        // 1
    const int xcd = bid % NXCD;
    const int i8  = bid / NXCD;
    const int wg  = (xcd < rem ? xcd * (quo + 1) : rem * (quo + 1) + (xcd - rem) * quo) + i8;
    const int l0  = wg * LPB;

    // Each thread computes rows (t>>7) and (t>>7)+2.
#pragma unroll
    for (int li = (t >> 7); li < LPB; li += 2) {
        const int l = l0 + li;
        const int row = l / 126;
        const int col = l - row * 126;
        float acc = 0.0f;
#pragma unroll
        for (int b3 = 0; b3 < 3; ++b3) {
#pragma unroll
            for (int j = 0; j < 3; ++j) {
                const unsigned phi = (unsigned)((3 * row + b3) * 378 + 3 * col + j);
                const unsigned n   = phi * 128u + (unsigned)q;  // fits u32
                const unsigned c   = n / 142884u;               // 378*378
                const unsigned rem2 = n - c * 142884u;
                const unsigned r   = rem2 / 378u;
                const unsigned ss  = rem2 - r * 378u;
                const unsigned src = c * 16384u + (r / 3u + r % 3u) * 128u + (ss / 3u + ss % 3u);
                acc = fmaf(x[src], lam[phi], acc);
            }
        }
        s[li * 128 + q] = fmaxf(acc, 0.0f);
    }
    __syncthreads();

    // Broadcast to 64 filter planes; nontemporal f4 stores, 2KB run per filter.
    const f4* s4 = (const f4*)s;       // 128 f4 covering the 4 rows
    f4* out4 = (f4*)out;
    const size_t lbase = (size_t)l0 * 32;
#pragma unroll
    for (int i = 0; i < 32; ++i) {
        const int idx = i * 256 + t;   // 0..8191
        const int f = idx >> 7;        // filter 0..63
        const int v = idx & 127;       // f4 index within 4-row chunk
        __builtin_nontemporal_store(s4[v], &out4[(size_t)f * L32 + lbase + v]);
    }
}

extern "C" void kernel_launch(void* const* d_in, const int* in_sizes, int n_in,
                              void* d_out, int out_size, void* d_ws, size_t ws_size,
                              hipStream_t stream) {
    const float* x   = (const float*)d_in[0];   // (1,128,128,128) f32
    const float* lam = (const float*)d_in[1];   // (1, 142884) f32
    float* out = (float*)d_out;                 // (64,126,126,128) f32

    spectral_kernel<<<NWG, 256, 0, stream>>>(x, lam, out);
}